// Round 1
// baseline (485.222 us; speedup 1.0000x reference)
//
#include <hip/hip_runtime.h>

// Cumulative average along last axis: y[..., t] = cumsum(x)[..., t] / (t+1)
// x: fp32, shape (8, 512, 16384) -> 4096 independent rows of T=16384.
//
// v2 structure: whole row in registers. One block per row, 512 threads,
// 32 contiguous elements per thread (8 float4 loads, ALL issued before any
// dependent use -> single HBM latency exposure per row instead of 16).
// Then exactly ONE wave shfl-scan + ONE LDS wave-total combine + ONE
// __syncthreads per row (vs 16 scans + 32 barriers in v1).
// Divide replaced by v_rcp_f32 * (rel err ~2^-22, tolerance is 2e-3).

#define ROW_T   16384
#define THREADS 512
#define EPT     (ROW_T / THREADS)   // 32 elements per thread (contiguous)
#define NV      (EPT / 4)           // 8 float4 loads per thread
#define NWAVES  (THREADS / 64)      // 8 waves

__global__ __launch_bounds__(THREADS)
void cumavg_kernel(const float* __restrict__ x, float* __restrict__ y) {
    const int  row  = blockIdx.x;
    const long base = (long)row * ROW_T;
    const int  tid  = threadIdx.x;
    const int  lane = tid & 63;
    const int  wave = tid >> 6;

    __shared__ float wsum[NWAVES];

    const float* px = x + base + (long)tid * EPT;
    float*       py = y + base + (long)tid * EPT;

    // ---- Load entire per-thread chunk: 8 independent float4 loads in flight
    float4 v[NV];
    #pragma unroll
    for (int j = 0; j < NV; ++j)
        v[j] = reinterpret_cast<const float4*>(px)[j];

    // ---- Thread-local total (tree-shaped to shorten the dep chain)
    float ts = 0.0f;
    #pragma unroll
    for (int j = 0; j < NV; ++j)
        ts += (v[j].x + v[j].y) + (v[j].z + v[j].w);

    // ---- Single wave-64 inclusive scan of per-thread sums
    float inc = ts;
    #pragma unroll
    for (int d = 1; d < 64; d <<= 1) {
        float n = __shfl_up(inc, d, 64);
        if (lane >= d) inc += n;
    }

    // ---- Publish wave totals, combine (one barrier per row)
    if (lane == 63) wsum[wave] = inc;
    __syncthreads();

    float woff = 0.0f;
    #pragma unroll
    for (int w = 0; w < NWAVES; ++w) {
        float s = wsum[w];
        woff += (w < wave) ? s : 0.0f;
    }

    // Exclusive prefix for this thread's first element
    float run = woff + (inc - ts);

    // ---- Emit 32 outputs: running sum * rcp(index)
    const int tbase = tid * EPT;
    #pragma unroll
    for (int j = 0; j < NV; ++j) {
        const float idx = (float)(tbase + j * 4 + 1);
        float4 o;
        run += v[j].x; o.x = run * __builtin_amdgcn_rcpf(idx);
        run += v[j].y; o.y = run * __builtin_amdgcn_rcpf(idx + 1.0f);
        run += v[j].z; o.z = run * __builtin_amdgcn_rcpf(idx + 2.0f);
        run += v[j].w; o.w = run * __builtin_amdgcn_rcpf(idx + 3.0f);
        reinterpret_cast<float4*>(py)[j] = o;
    }
}

extern "C" void kernel_launch(void* const* d_in, const int* in_sizes, int n_in,
                              void* d_out, int out_size, void* d_ws, size_t ws_size,
                              hipStream_t stream) {
    const float* x = (const float*)d_in[0];
    float*       y = (float*)d_out;
    const int rows = in_sizes[0] / ROW_T;   // 8*512 = 4096
    hipLaunchKernelGGL(cumavg_kernel, dim3(rows), dim3(THREADS), 0, stream, x, y);
}

// Round 3
// 455.442 us; speedup vs baseline: 1.0654x; 1.0654x over previous
//
#include <hip/hip_runtime.h>

// Cumulative average along last axis: y[..., t] = cumsum(x)[..., t] / (t+1)
// x: fp32, shape (8, 512, 16384) -> 4096 independent rows of T=16384.
//
// v3b: whole row in registers with COALESCED layout (compile-fixed v3).
//   - thread tid owns float4 slot (tid*4) of each of the 16 tiles
//     -> every load/store instruction is perfectly coalesced (1 KiB/wave)
//   - all 16 loads issued back-to-back: ONE HBM latency exposure per row
//   - 16 independent wave shfl-scans, interleaved (DS-pipe ILP, no
//     inter-tile serialization), ONE LDS publish + ONE barrier per row
//   - in-register prefix over tile totals, 16 coalesced float4 stores
//   - nontemporal stores via clang ext_vector type (HIP float4 is a
//     struct -> rejected by __builtin_nontemporal_store)
//   - divide via v_rcp_f32 * (rel err ~2^-22 << 2e-3 tolerance)

#define ROW_T   16384
#define THREADS 256
#define VEC     4
#define TILE    (THREADS * VEC)    // 1024 elements per tile
#define NT      (ROW_T / TILE)     // 16 tiles per row
#define NWAVES  (THREADS / 64)     // 4 waves

typedef float f32x4 __attribute__((ext_vector_type(4)));

__global__ __launch_bounds__(THREADS)
void cumavg_kernel(const float* __restrict__ x, float* __restrict__ y) {
    const int  row  = blockIdx.x;
    const long base = (long)row * ROW_T;
    const int  tid  = threadIdx.x;
    const int  lane = tid & 63;
    const int  wave = tid >> 6;

    __shared__ float wsum[NT][NWAVES];

    const float* px = x + base + (long)tid * VEC;
    float*       py = y + base + (long)tid * VEC;

    // ---- Load the whole row, coalesced, all loads in flight at once
    f32x4 v[NT];
    #pragma unroll
    for (int t = 0; t < NT; ++t)
        v[t] = *reinterpret_cast<const f32x4*>(px + t * TILE);

    // ---- Per-tile thread-local sums (tree adds)
    float ts[NT];
    #pragma unroll
    for (int t = 0; t < NT; ++t)
        ts[t] = (v[t].x + v[t].y) + (v[t].z + v[t].w);

    // ---- 16 independent wave-64 inclusive scans, interleaved for ILP
    float inc[NT];
    #pragma unroll
    for (int t = 0; t < NT; ++t) inc[t] = ts[t];

    #pragma unroll
    for (int d = 1; d < 64; d <<= 1) {
        #pragma unroll
        for (int t = 0; t < NT; ++t) {
            float n = __shfl_up(inc[t], d, 64);
            if (lane >= d) inc[t] += n;
        }
    }

    // ---- Publish all wave totals at once; single barrier per row
    if (lane == 63) {
        #pragma unroll
        for (int t = 0; t < NT; ++t) wsum[t][wave] = inc[t];
    }
    __syncthreads();

    // ---- Combine + emit. run = sum of all previous tiles' totals.
    float run = 0.0f;
    #pragma unroll
    for (int t = 0; t < NT; ++t) {
        float woff = 0.0f, tot = 0.0f;
        #pragma unroll
        for (int w = 0; w < NWAVES; ++w) {
            float s = wsum[t][w];          // broadcast read: conflict-free
            tot  += s;
            woff += (w < wave) ? s : 0.0f;
        }

        // Exclusive prefix for this thread's first element of tile t
        float ex = run + woff + (inc[t] - ts[t]);

        const int off = t * TILE + tid * VEC;  // position within the row
        float s0 = ex + v[t].x;
        float s1 = s0 + v[t].y;
        float s2 = s1 + v[t].z;
        float s3 = s2 + v[t].w;

        f32x4 o;
        o.x = s0 * __builtin_amdgcn_rcpf((float)(off + 1));
        o.y = s1 * __builtin_amdgcn_rcpf((float)(off + 2));
        o.z = s2 * __builtin_amdgcn_rcpf((float)(off + 3));
        o.w = s3 * __builtin_amdgcn_rcpf((float)(off + 4));

        __builtin_nontemporal_store(o, reinterpret_cast<f32x4*>(py + t * TILE));

        run += tot;
    }
}

extern "C" void kernel_launch(void* const* d_in, const int* in_sizes, int n_in,
                              void* d_out, int out_size, void* d_ws, size_t ws_size,
                              hipStream_t stream) {
    const float* x = (const float*)d_in[0];
    float*       y = (float*)d_out;
    const int rows = in_sizes[0] / ROW_T;   // 8*512 = 4096
    hipLaunchKernelGGL(cumavg_kernel, dim3(rows), dim3(THREADS), 0, stream, x, y);
}

// Round 4
// 452.564 us; speedup vs baseline: 1.0722x; 1.0064x over previous
//
#include <hip/hip_runtime.h>

// Cumulative average along last axis: y[..., t] = cumsum(x)[..., t] / (t+1)
// x: fp32, shape (8, 512, 16384) -> 4096 independent rows of T=16384.
//
// v4: v3b structure (coalesced row-in-registers, one barrier per row) but
// register footprint halved to kill the AGPR round-trip and double occupancy:
//   - 512 threads/block, thread owns float4 slot (tid*4) in each of 8 tiles
//     -> v[8]=32 VGPRs + inc[8]+ts[8] ~ 60 VGPRs total (v3b: ~128 w/ AGPR spill)
//   - up to 8 waves/SIMD resident -> 4 blocks/CU overlapping their
//     load/scan/emit phases -> VMEM pipe stays fed
//   - 8 independent wave shfl-scans interleaved; ONE barrier per row
//   - nontemporal float4 stores (preserve input L3 residency)
//   - divide via v_rcp_f32 * (rel err ~2^-22 << 2e-3 tolerance)

#define ROW_T   16384
#define THREADS 512
#define VEC     4
#define TILE    (THREADS * VEC)    // 2048 elements per tile
#define NT      (ROW_T / TILE)     // 8 tiles per row
#define NWAVES  (THREADS / 64)     // 8 waves

typedef float f32x4 __attribute__((ext_vector_type(4)));

__global__ __launch_bounds__(THREADS, 4)
void cumavg_kernel(const float* __restrict__ x, float* __restrict__ y) {
    const int  row  = blockIdx.x;
    const long base = (long)row * ROW_T;
    const int  tid  = threadIdx.x;
    const int  lane = tid & 63;
    const int  wave = tid >> 6;

    __shared__ float wsum[NT][NWAVES];

    const float* px = x + base + (long)tid * VEC;
    float*       py = y + base + (long)tid * VEC;

    // ---- Load the whole row, coalesced, all loads in flight at once
    f32x4 v[NT];
    #pragma unroll
    for (int t = 0; t < NT; ++t)
        v[t] = *reinterpret_cast<const f32x4*>(px + t * TILE);

    // ---- Per-tile thread-local sums (tree adds)
    float ts[NT];
    #pragma unroll
    for (int t = 0; t < NT; ++t)
        ts[t] = (v[t].x + v[t].y) + (v[t].z + v[t].w);

    // ---- 8 independent wave-64 inclusive scans, interleaved for ILP
    float inc[NT];
    #pragma unroll
    for (int t = 0; t < NT; ++t) inc[t] = ts[t];

    #pragma unroll
    for (int d = 1; d < 64; d <<= 1) {
        #pragma unroll
        for (int t = 0; t < NT; ++t) {
            float n = __shfl_up(inc[t], d, 64);
            if (lane >= d) inc[t] += n;
        }
    }

    // ---- Publish all wave totals at once; single barrier per row
    if (lane == 63) {
        #pragma unroll
        for (int t = 0; t < NT; ++t) wsum[t][wave] = inc[t];
    }
    __syncthreads();

    // ---- Combine + emit. run = sum of all previous tiles' totals.
    float run = 0.0f;
    #pragma unroll
    for (int t = 0; t < NT; ++t) {
        float woff = 0.0f, tot = 0.0f;
        #pragma unroll
        for (int w = 0; w < NWAVES; ++w) {
            float s = wsum[t][w];          // broadcast read: conflict-free
            tot  += s;
            woff += (w < wave) ? s : 0.0f;
        }

        // Exclusive prefix for this thread's first element of tile t
        float ex = run + woff + (inc[t] - ts[t]);

        const int off = t * TILE + tid * VEC;  // position within the row
        float s0 = ex + v[t].x;
        float s1 = s0 + v[t].y;
        float s2 = s1 + v[t].z;
        float s3 = s2 + v[t].w;

        f32x4 o;
        o.x = s0 * __builtin_amdgcn_rcpf((float)(off + 1));
        o.y = s1 * __builtin_amdgcn_rcpf((float)(off + 2));
        o.z = s2 * __builtin_amdgcn_rcpf((float)(off + 3));
        o.w = s3 * __builtin_amdgcn_rcpf((float)(off + 4));

        __builtin_nontemporal_store(o, reinterpret_cast<f32x4*>(py + t * TILE));

        run += tot;
    }
}

extern "C" void kernel_launch(void* const* d_in, const int* in_sizes, int n_in,
                              void* d_out, int out_size, void* d_ws, size_t ws_size,
                              hipStream_t stream) {
    const float* x = (const float*)d_in[0];
    float*       y = (float*)d_out;
    const int rows = in_sizes[0] / ROW_T;   // 8*512 = 4096
    hipLaunchKernelGGL(cumavg_kernel, dim3(rows), dim3(THREADS), 0, stream, x, y);
}